// Round 1
// baseline (487.093 us; speedup 1.0000x reference)
//
#include <hip/hip_runtime.h>

#define DIM 128
#define SCAN_TPB 256
#define SCAN_EPB 2048  // 8 elements per thread

// ---------- build-phase kernels ----------

__global__ void init_counts(int* deg_out, int* cnt_in, int n) {
    int i = blockIdx.x * blockDim.x + threadIdx.x;
    if (i < n) { deg_out[i] = 1; cnt_in[i] = 1; }  // self-loop contributes 1 to each
}

__global__ void count_edges(const int2* __restrict__ edges, int E,
                            int* deg_out, int* cnt_in) {
    int e = blockIdx.x * blockDim.x + threadIdx.x;
    if (e < E) {
        int2 ed = edges[e];               // ed.x = src, ed.y = dst
        atomicAdd(&deg_out[ed.x], 1);     // reference deg = segment_sum over src_all
        atomicAdd(&cnt_in[ed.y], 1);      // in-degree for CSR-by-dst
    }
}

__global__ void compute_dinv(const int* __restrict__ deg, float* dinv, int n) {
    int i = blockIdx.x * blockDim.x + threadIdx.x;
    if (i < n) dinv[i] = rsqrtf((float)deg[i]);   // deg >= 1 always (self-loop)
}

// Block-level exclusive scan: each block handles 2048 elems (8/thread).
__global__ void scan1(const int* __restrict__ cnt, int n,
                      int* __restrict__ out, int* __restrict__ bsums) {
    __shared__ int sdata[SCAN_TPB];
    int tid = threadIdx.x;
    int base = blockIdx.x * SCAN_EPB + tid * 8;
    int v[8]; int s = 0;
    #pragma unroll
    for (int i = 0; i < 8; i++) {
        int idx = base + i;
        v[i] = (idx < n) ? cnt[idx] : 0;
        s += v[i];
    }
    sdata[tid] = s;
    __syncthreads();
    // Hillis-Steele inclusive scan of thread sums
    for (int off = 1; off < SCAN_TPB; off <<= 1) {
        int t = (tid >= off) ? sdata[tid - off] : 0;
        __syncthreads();
        sdata[tid] += t;
        __syncthreads();
    }
    int thread_prefix = sdata[tid] - s;   // exclusive
    int run = thread_prefix;
    #pragma unroll
    for (int i = 0; i < 8; i++) {
        int idx = base + i;
        if (idx < n) out[idx] = run;
        run += v[i];
    }
    if (tid == SCAN_TPB - 1) bsums[blockIdx.x] = sdata[SCAN_TPB - 1];
}

__global__ void scan2(int* bsums, int nblk) {
    if (blockIdx.x == 0 && threadIdx.x == 0) {
        int run = 0;
        for (int i = 0; i < nblk; i++) { int v = bsums[i]; bsums[i] = run; run += v; }
    }
}

__global__ void scan3(int* rowoff, const int* __restrict__ bsums,
                      int* fill_ptr, int n, int total) {
    int i = blockIdx.x * blockDim.x + threadIdx.x;
    if (i < n) {
        int v = rowoff[i] + bsums[i >> 11];   // 2048 = 1<<11
        rowoff[i] = v;
        fill_ptr[i] = v;
    }
    if (i == 0) rowoff[n] = total;
}

__global__ void fill_csr(const int2* __restrict__ edges, int E, int N,
                         const float* __restrict__ dinv,
                         int* fill_ptr, int* __restrict__ csr_src,
                         float* __restrict__ csr_norm) {
    int i = blockIdx.x * blockDim.x + threadIdx.x;
    if (i < E) {
        int2 ed = edges[i];
        int p = atomicAdd(&fill_ptr[ed.y], 1);
        csr_src[p] = ed.x;
        csr_norm[p] = dinv[ed.x] * dinv[ed.y];
    } else if (i < E + N) {
        int v = i - E;
        int p = atomicAdd(&fill_ptr[v], 1);
        csr_src[p] = v;
        float dv = dinv[v];
        csr_norm[p] = dv * dv;
    }
}

// ---------- layer kernel: one wave64 per node, float2 per lane ----------

__global__ __launch_bounds__(256) void gcn_layer(
    const float* __restrict__ xin, const int* __restrict__ rowoff,
    const int* __restrict__ csr_src, const float* __restrict__ csr_norm,
    const float* __restrict__ w, const float* __restrict__ b,
    float* __restrict__ xout, int N, int do_relu) {
    int node = blockIdx.x * (blockDim.x >> 6) + (threadIdx.x >> 6);
    if (node >= N) return;
    int lane = threadIdx.x & 63;
    int start = __builtin_amdgcn_readfirstlane(rowoff[node]);
    int end   = __builtin_amdgcn_readfirstlane(rowoff[node + 1]);
    const float2* x2 = (const float2*)xin;
    float ax = 0.f, ay = 0.f;
    for (int k = start; k < end; ++k) {
        int s = csr_src[k];       // wave-uniform address -> broadcast
        float nrm = csr_norm[k];
        float2 xv = x2[(size_t)s * 64 + lane];   // 512B coalesced row read
        ax = fmaf(nrm, xv.x, ax);
        ay = fmaf(nrm, xv.y, ay);
    }
    int d = lane * 2;
    float o0 = fmaf(ax, w[d],     b[d]);
    float o1 = fmaf(ay, w[d + 1], b[d + 1]);
    if (do_relu) { o0 = fmaxf(o0, 0.f); o1 = fmaxf(o1, 0.f); }
    ((float2*)xout)[(size_t)node * 64 + lane] = make_float2(o0, o1);
}

// ---------- launch ----------

static inline size_t align256(size_t x) { return (x + 255) & ~(size_t)255; }

extern "C" void kernel_launch(void* const* d_in, const int* in_sizes, int n_in,
                              void* d_out, int out_size, void* d_ws, size_t ws_size,
                              hipStream_t stream) {
    const int2*  edges = (const int2*)d_in[0];
    const float* x     = (const float*)d_in[1];
    const float* w1    = (const float*)d_in[2];
    const float* b1    = (const float*)d_in[3];
    const float* w2    = (const float*)d_in[4];
    const float* b2    = (const float*)d_in[5];
    float* out = (float*)d_out;

    const int E = in_sizes[0] / 2;
    const int N = in_sizes[1] / DIM;
    const int TOT = E + N;

    // workspace carve-up
    char* p = (char*)d_ws;
    int*   deg_out  = (int*)p;              p += align256((size_t)N * 4);
    int*   cnt_in   = (int*)p;              p += align256((size_t)N * 4);
    float* dinv     = (float*)p;            p += align256((size_t)N * 4);
    int*   rowoff   = (int*)p;              p += align256((size_t)(N + 1) * 4);
    int*   fill_ptr = (int*)p;              p += align256((size_t)N * 4);
    int*   bsums    = (int*)p;              p += align256((size_t)256 * 4);
    int*   csr_src  = (int*)p;              p += align256((size_t)TOT * 4);
    float* csr_norm = (float*)p;            p += align256((size_t)TOT * 4);
    float* h        = (float*)p;            p += align256((size_t)N * DIM * 4);

    const int TPB = 256;
    int nbN = (N + TPB - 1) / TPB;
    int nbE = (E + TPB - 1) / TPB;
    int nbT = (TOT + TPB - 1) / TPB;
    int nscan = (N + SCAN_EPB - 1) / SCAN_EPB;

    init_counts<<<nbN, TPB, 0, stream>>>(deg_out, cnt_in, N);
    count_edges<<<nbE, TPB, 0, stream>>>(edges, E, deg_out, cnt_in);
    compute_dinv<<<nbN, TPB, 0, stream>>>(deg_out, dinv, N);
    scan1<<<nscan, SCAN_TPB, 0, stream>>>(cnt_in, N, rowoff, bsums);
    scan2<<<1, 64, 0, stream>>>(bsums, nscan);
    scan3<<<nbN, TPB, 0, stream>>>(rowoff, bsums, fill_ptr, N, TOT);
    fill_csr<<<nbT, TPB, 0, stream>>>(edges, E, N, dinv, fill_ptr, csr_src, csr_norm);

    int waves_per_block = 4;  // 256 threads
    int nbL = (N + waves_per_block - 1) / waves_per_block;
    gcn_layer<<<nbL, 256, 0, stream>>>(x, rowoff, csr_src, csr_norm, w1, b1, h, N, 1);
    gcn_layer<<<nbL, 256, 0, stream>>>(h, rowoff, csr_src, csr_norm, w2, b2, out, N, 0);
}